// Round 4
// baseline (106.204 us; speedup 1.0000x reference)
//
#include <hip/hip_runtime.h>

namespace {
constexpr int kB = 16384;
constexpr int kC = 1000;
constexpr int kNElem = kB * kC;          // 16,384,000
constexpr int kNV8 = kNElem / 8;         // 2,048,000
constexpr int kV8PerRow = kC / 8;        // 125
constexpr int kBlocks = 1024;            // proven-best grid (R1)
constexpr int kThreads = 256;
constexpr int kWaves = kThreads / 64;    // 4
constexpr int kCopies = 16;              // sub-histograms per wave (4 lanes share one)
constexpr int kHistWords = kWaves * kCopies * 10;  // 640
}

// ws layout (20 x 4B): wsf[0..9] = float S_k (bce sum per bin),
//                      wsu[10..19] = uint N_k (count per bin)

__global__ __launch_bounds__(kThreads) void ghmc_main(
    const float* __restrict__ logits,
    const int* __restrict__ tgt,
    float* __restrict__ wsf)
{
    __shared__ float    s_sum[kHistWords];
    __shared__ unsigned s_cnt[kHistWords];

    for (int t = threadIdx.x; t < kHistWords; t += kThreads) {
        s_sum[t] = 0.f;
        s_cnt[t] = 0u;
    }
    __syncthreads();

    const int wave = threadIdx.x >> 6;
    const int lane = threadIdx.x & 63;
    float*    const hsum = &s_sum[(wave * kCopies + (lane & (kCopies - 1))) * 10];
    unsigned* const hcnt = &s_cnt[(wave * kCopies + (lane & (kCopies - 1))) * 10];

    const int stride = gridDim.x * blockDim.x;
    for (int i = blockIdx.x * blockDim.x + threadIdx.x; i < kNV8; i += stride) {
        const int row = i / kV8PerRow;                        // magic-mul div
        const int dt  = tgt[row] - (i - row * kV8PerRow) * 8; // rare-branch only
        float lv[8];
        *reinterpret_cast<float4*>(&lv[0]) = reinterpret_cast<const float4*>(logits)[2 * i];
        *reinterpret_cast<float4*>(&lv[4]) = reinterpret_cast<const float4*>(logits)[2 * i + 1];

        // main path: assume non-target (s = L); pure function of the loaded data
        #pragma unroll
        for (int e = 0; e < 8; ++e) {
            const float L   = lv[e];
            const float en  = __expf(-fabsf(L));          // exp(-|L|)
            const float den = 1.f + en;
            const float r   = __builtin_amdgcn_rcpf(den); // ~1ulp approx
            // 10*sigmoid(L): L>=0 -> 10/(1+en); L<0 -> 10*en/(1+en)
            const float num = (L >= 0.f) ? 10.f : 10.f * en;
            const float g10 = num * r;                    // in [0, 10)
            unsigned b = (unsigned)g10;                   // trunc == floor (g10>=0)
            b = b > 9u ? 9u : b;
            const float bce = fmaxf(L, 0.f) + __logf(den); // softplus(L)
            atomicAdd(&hsum[b], bce);                     // ds_add_f32
            atomicAdd(&hcnt[b], 1u);                      // ds_add_u32
        }

        // rare correction: this 8-chunk contains the row's target element
        if (__builtin_expect((unsigned)dt < 8u, 0)) {
            float L = lv[0];
            #pragma unroll
            for (int e = 1; e < 8; ++e) L = (dt == e) ? lv[e] : L;
            const float en  = __expf(-fabsf(L));
            const float den = 1.f + en;
            const float r   = __builtin_amdgcn_rcpf(den);
            const float lg  = __logf(den);
            // undo the non-target contribution
            const float numn = (L >= 0.f) ? 10.f : 10.f * en;
            unsigned bn = (unsigned)(numn * r); bn = bn > 9u ? 9u : bn;
            const float bcen = fmaxf(L, 0.f) + lg;
            // apply the target contribution: s = -L, sigmoid(-L)=1-sigmoid(L)
            const float numt = (L <= 0.f) ? 10.f : 10.f * en;
            unsigned bt = (unsigned)(numt * r); bt = bt > 9u ? 9u : bt;
            const float bcet = fmaxf(-L, 0.f) + lg;
            atomicAdd(&hsum[bn], -bcen);
            atomicAdd(&hcnt[bn], 0xFFFFFFFFu);  // -1 (wraps correctly)
            atomicAdd(&hsum[bt],  bcet);
            atomicAdd(&hcnt[bt], 1u);
        }
    }

    __syncthreads();
    // fold 64 copies -> 10 bins, one global atomic per bin per block
    if (threadIdx.x < 10) {
        const int b = threadIdx.x;
        float acc = 0.f;
        #pragma unroll
        for (int c = 0; c < kWaves * kCopies; ++c) acc += s_sum[c * 10 + b];
        atomicAdd(&wsf[b], acc);
    } else if (threadIdx.x < 20) {
        const int b = threadIdx.x - 10;
        unsigned acc = 0u;
        #pragma unroll
        for (int c = 0; c < kWaves * kCopies; ++c) acc += s_cnt[c * 10 + b];
        atomicAdd(reinterpret_cast<unsigned*>(wsf) + 10 + b, acc);
    }
}

__global__ void ghmc_final(const float* __restrict__ wsf, float* __restrict__ out)
{
    if (threadIdx.x == 0 && blockIdx.x == 0) {
        const unsigned* wsu = reinterpret_cast<const unsigned*>(wsf) + 10;
        float acc = 0.f, n = 0.f;
        #pragma unroll
        for (int k = 0; k < 10; ++k) {
            const float Nk = (float)wsu[k];
            if (Nk > 0.f) { n += 1.f; acc += wsf[k] / Nk; }
        }
        out[0] = acc / fmaxf(n, 1.f);   // loss = (1/n) * sum_k S_k/N_k, LOSS_WEIGHT=1
    }
}

extern "C" void kernel_launch(void* const* d_in, const int* in_sizes, int n_in,
                              void* d_out, int out_size, void* d_ws, size_t ws_size,
                              hipStream_t stream)
{
    const float* logits = (const float*)d_in[0];
    const int*   tgt    = (const int*)d_in[1];
    float* wsf = (float*)d_ws;
    hipMemsetAsync(d_ws, 0, 20 * sizeof(float), stream);
    ghmc_main<<<kBlocks, kThreads, 0, stream>>>(logits, tgt, wsf);
    ghmc_final<<<1, 64, 0, stream>>>(wsf, (float*)d_out);
}

// Round 5
// 62.482 us; speedup vs baseline: 1.6998x; 1.6998x over previous
//
#include <hip/hip_runtime.h>

typedef float v2f __attribute__((ext_vector_type(2)));

namespace {
constexpr int kB = 16384;
constexpr int kC = 1000;
constexpr int kNElem = kB * kC;           // 16,384,000
constexpr int kNV4 = kNElem / 4;          // 4,096,000
constexpr int kV4PerRow = kC / 4;         // 250
constexpr int kBlocks = 1024;             // R1's proven grid
constexpr int kThreads = 256;
constexpr double kScale = 1048576.0;      // 2^20 fixed-point for i64 sum atomics
}

// ws layout: wsll[0..9] (u64 fixed-point hinge sums; slot0 = T with c=0),
//            wsu[0..8]  (u32 thermometer counts, index j-1 for j=1..9)
//
// Identity: acc_j = sum over all elements of max(bce, c_j)
//           cum_j = sum_{bce>=c_j} bce = acc_j - c_j*(N - cnt_j)   (done in f64)
// where c_j = softplus(th_j) = -ln(1 - j/10); bce = softplus(s) monotone in s.

__global__ __launch_bounds__(kThreads) void ghmc_main(
    const float* __restrict__ logits,
    const int* __restrict__ tgt,
    unsigned long long* __restrict__ wsll,
    unsigned* __restrict__ wsu)
{
    // hinge constant pairs (slot0 c=0 accumulates T exactly since bce>0)
    const v2f C01 = {0.0f,        0.10536052f};
    const v2f C23 = {0.22314355f, 0.35667494f};
    const v2f C45 = {0.51082562f, 0.69314718f};
    const v2f C67 = {0.91629073f, 1.20397280f};
    const v2f C89 = {1.60943791f, 2.30258509f};

    v2f a01 = {0.f, 0.f}, a23 = {0.f, 0.f}, a45 = {0.f, 0.f},
        a67 = {0.f, 0.f}, a89 = {0.f, 0.f};
    int c1 = 0, c3 = 0, c5 = 0, c7 = 0;                 // per-lane addc bins
    unsigned w2 = 0, w4 = 0, w6 = 0, w8 = 0, w9 = 0;    // wave-uniform ballot bins

    const int stride = gridDim.x * blockDim.x;
    for (int i = blockIdx.x * blockDim.x + threadIdx.x; i < kNV4; i += stride) {
        const int row = i / kV4PerRow;                   // magic-mul division
        const int dt  = tgt[row] - (i - row * kV4PerRow) * 4;
        const float4 v = reinterpret_cast<const float4*>(logits)[i];
        const float lv[4] = {v.x, v.y, v.z, v.w};
        #pragma unroll
        for (int e = 0; e < 4; ++e) {
            const float L     = lv[e];
            const float en    = __builtin_amdgcn_exp2f(-1.4426950408889634f * fabsf(L));
            const float den   = 1.f + en;
            const float maxL0 = fmaxf(L, 0.f);
            const float sub   = (dt == e) ? L : 0.f;     // target: softplus(-L)=softplus(L)-L
            // bce = max(s,0) + log1p(exp(-|s|)) = maxL0 - sub + ln2*log2(den)
            const float bce = fmaf(__builtin_amdgcn_logf(den), 0.6931471805599453f, maxL0) - sub;

            const v2f b2 = {bce, bce};
            a01 += __builtin_elementwise_max(b2, C01);   // v_pk_max + v_pk_add
            a23 += __builtin_elementwise_max(b2, C23);
            a45 += __builtin_elementwise_max(b2, C45);
            a67 += __builtin_elementwise_max(b2, C67);
            a89 += __builtin_elementwise_max(b2, C89);

            c1 += (bce >= 0.10536052f);                  // v_cmp + v_addc
            c3 += (bce >= 0.35667494f);
            c5 += (bce >= 0.69314718f);
            c7 += (bce >= 1.20397280f);
            w2 += (unsigned)__popcll(__ballot(bce >= 0.22314355f));  // SALU bcnt+add
            w4 += (unsigned)__popcll(__ballot(bce >= 0.51082562f));
            w6 += (unsigned)__popcll(__ballot(bce >= 0.91629073f));
            w8 += (unsigned)__popcll(__ballot(bce >= 1.60943791f));
            w9 += (unsigned)__popcll(__ballot(bce >= 2.30258509f));
        }
    }

    // lane-reduce the 10 floats + 4 ints across the wave
    float r[10] = {a01.x, a01.y, a23.x, a23.y, a45.x, a45.y, a67.x, a67.y, a89.x, a89.y};
    #pragma unroll
    for (int off = 32; off > 0; off >>= 1) {
        #pragma unroll
        for (int k = 0; k < 10; ++k) r[k] += __shfl_down(r[k], off);
        c1 += __shfl_down(c1, off);
        c3 += __shfl_down(c3, off);
        c5 += __shfl_down(c5, off);
        c7 += __shfl_down(c7, off);
    }

    __shared__ float    sf[4][10];
    __shared__ int      si[4][4];
    __shared__ unsigned su[4][5];
    const int wave = threadIdx.x >> 6;
    const int lane = threadIdx.x & 63;
    if (lane == 0) {
        #pragma unroll
        for (int k = 0; k < 10; ++k) sf[wave][k] = r[k];
        si[wave][0] = c1; si[wave][1] = c3; si[wave][2] = c5; si[wave][3] = c7;
        su[wave][0] = w2; su[wave][1] = w4; su[wave][2] = w6; su[wave][3] = w8; su[wave][4] = w9;
    }
    __syncthreads();
    const int t = threadIdx.x;
    if (t < 10) {
        const float s = sf[0][t] + sf[1][t] + sf[2][t] + sf[3][t];
        atomicAdd(&wsll[t], (unsigned long long)(long long)((double)s * kScale));
    } else if (t < 14) {
        const int q = t - 10;                              // bins j = 1,3,5,7
        const unsigned s = (unsigned)(si[0][q] + si[1][q] + si[2][q] + si[3][q]);
        atomicAdd(&wsu[2 * q], s);                         // wsu[j-1]
    } else if (t < 19) {
        const int q = t - 14;                              // bins j = 2,4,6,8,9
        const unsigned s = su[0][q] + su[1][q] + su[2][q] + su[3][q];
        const int idx = (t < 18) ? (2 * q + 1) : 8;        // wsu[j-1]
        atomicAdd(&wsu[idx], s);
    }
}

__global__ void ghmc_final(const unsigned long long* __restrict__ wsll,
                           const unsigned* __restrict__ wsu,
                           float* __restrict__ out)
{
    if (threadIdx.x == 0 && blockIdx.x == 0) {
        const double cj[10] = {0.0,
            0.10536051565782630, 0.22314355131420976, 0.35667494393873245,
            0.51082562376599072, 0.69314718055994531, 0.91629073187415511,
            1.20397280432593600, 1.60943791243410040, 2.30258509299404570};
        double cum[11];
        double cnt[11];
        cnt[0] = (double)kNElem;
        cum[0] = (double)wsll[0] / kScale;     // T (c=0 hinge is exact)
        for (int j = 1; j <= 9; ++j) {
            cnt[j] = (double)wsu[j - 1];
            const double acc = (double)wsll[j] / kScale;
            cum[j] = acc - cj[j] * ((double)kNElem - cnt[j]);
        }
        cum[10] = 0.0; cnt[10] = 0.0;
        double loss = 0.0, n = 0.0;
        for (int k = 0; k < 10; ++k) {
            const double Nk = cnt[k] - cnt[k + 1];
            if (Nk > 0.0) {
                n += 1.0;
                loss += (cum[k] - cum[k + 1]) / Nk;
            }
        }
        out[0] = (float)(loss / (n > 1.0 ? n : 1.0));
    }
}

extern "C" void kernel_launch(void* const* d_in, const int* in_sizes, int n_in,
                              void* d_out, int out_size, void* d_ws, size_t ws_size,
                              hipStream_t stream)
{
    const float* logits = (const float*)d_in[0];
    const int*   tgt    = (const int*)d_in[1];
    unsigned long long* wsll = (unsigned long long*)d_ws;        // 10 x u64
    unsigned*           wsu  = (unsigned*)((char*)d_ws + 80);    // 9 x u32
    hipMemsetAsync(d_ws, 0, 128, stream);
    ghmc_main<<<kBlocks, kThreads, 0, stream>>>(logits, tgt, wsll, wsu);
    ghmc_final<<<1, 64, 0, stream>>>(wsll, wsu, (float*)d_out);
}

// Round 6
// 55.427 us; speedup vs baseline: 1.9161x; 1.1273x over previous
//
#include <hip/hip_runtime.h>

typedef float v2f __attribute__((ext_vector_type(2)));

namespace {
constexpr int kB = 16384;
constexpr int kC = 1000;
constexpr int kNElem = kB * kC;           // 16,384,000
constexpr int kNV4 = kNElem / 4;          // 4,096,000
constexpr int kV4PerRow = kC / 4;         // 250
constexpr int kBlocks = 1280;             // 5 blk/CU; <=13 iters/thread -> <=52 elems
                                          // -> 6-bit count fields can never overflow
constexpr int kThreads = 256;
constexpr double kScale = 1048576.0;      // 2^20 fixed point for u64 sum atomics
}

// ws: wsll[0..9] = u64 fixed-point hinge sums acc_j = sum max(bce, c_j) (c_0 = 0 -> T)
//     wsu[0..9]  = u32 per-bin counts N_k
// Identities (finalize, f64): cnt_j = sum_{k>=j} N_k;
//   cum_j = acc_j - c_j*(N_total - cnt_j);  S_k = cum_k - cum_{k+1};
//   loss = (1/n) sum_{N_k>0} S_k / N_k.

__global__ __launch_bounds__(kThreads) void ghmc_main(
    const float* __restrict__ logits,
    const int* __restrict__ tgt,
    unsigned long long* __restrict__ wsll,
    unsigned* __restrict__ wsu)
{
    // c_j = softplus(logit(j/10)) = -ln(1 - j/10); slot0 uses c=0 (bce>0 -> exact T)
    const v2f C01 = {0.0f,        0.10536052f};
    const v2f C23 = {0.22314355f, 0.35667494f};
    const v2f C45 = {0.51082562f, 0.69314718f};
    const v2f C67 = {0.91629073f, 1.20397280f};
    const v2f C89 = {1.60943791f, 2.30258509f};
    const float kLn2   = 0.6931471805599453f;
    const float kNRLn2 = -1.4426950408889634f;

    v2f a01 = {0.f,0.f}, a23 = {0.f,0.f}, a45 = {0.f,0.f},
        a67 = {0.f,0.f}, a89 = {0.f,0.f};
    unsigned long long hcnt = 0ull;       // 10 x 6-bit bin counts

    const int stride = gridDim.x * blockDim.x;
    for (int i = blockIdx.x * blockDim.x + threadIdx.x; i < kNV4; i += stride) {
        const int row = i / kV4PerRow;                        // magic-mul div
        const int dt  = tgt[row] - (i - row * kV4PerRow) * 4; // feeds rare branch only
        const float4 v = reinterpret_cast<const float4*>(logits)[i];
        const float lv[4] = {v.x, v.y, v.z, v.w};

        // main path: pure function of the float4 (non-target assumption s = L)
        #pragma unroll
        for (int e = 0; e < 4; ++e) {
            const float L   = lv[e];
            const float en  = __builtin_amdgcn_exp2f(kNRLn2 * fabsf(L)); // e^{-|L|}
            const float den = 1.f + en;
            const float lg  = __builtin_amdgcn_logf(den);   // log2(den)
            const float r   = __builtin_amdgcn_rcpf(den);   // trans pipe (idle)
            const float bce = fmaf(lg, kLn2, fmaxf(L, 0.f)); // softplus(L)

            // bin: sigmoid(|L|) = 1/(1+en) -> babs in [5,9]; mirror for L<0
            unsigned babs = (unsigned)(10.f * r);
            babs = babs > 9u ? 9u : babs;
            const unsigned bin = (L >= 0.f) ? babs : 9u - babs;
            hcnt += 1ull << (6u * bin);                     // mul24+lshl_b64+add64

            const v2f b2 = {bce, bce};
            a01 += __builtin_elementwise_max(b2, C01);
            a23 += __builtin_elementwise_max(b2, C23);
            a45 += __builtin_elementwise_max(b2, C45);
            a67 += __builtin_elementwise_max(b2, C67);
            a89 += __builtin_elementwise_max(b2, C89);
        }

        // rare correction: this 4-chunk holds the row's target element
        if (__builtin_expect((unsigned)dt < 4u, 0)) {
            float L = lv[0];
            #pragma unroll
            for (int e = 1; e < 4; ++e) L = (dt == e) ? lv[e] : L;
            const float en  = __builtin_amdgcn_exp2f(kNRLn2 * fabsf(L));
            const float den = 1.f + en;
            const float lg  = __builtin_amdgcn_logf(den);
            const float r   = __builtin_amdgcn_rcpf(den);
            const float bn_ = fmaf(lg, kLn2, fmaxf(L, 0.f)); // softplus(L), added by main
            const float bt_ = bn_ - L;                        // softplus(-L)
            unsigned babs = (unsigned)(10.f * r);
            babs = babs > 9u ? 9u : babs;
            const unsigned bn = (L >= 0.f) ? babs : 9u - babs;
            const unsigned bt = (L <= 0.f) ? babs : 9u - babs;
            hcnt += (1ull << (6u * bt)) - (1ull << (6u * bn)); // field >=1, no underflow
            const v2f bn2 = {bn_, bn_}, bt2 = {bt_, bt_};
            a01 += __builtin_elementwise_max(bt2, C01) - __builtin_elementwise_max(bn2, C01);
            a23 += __builtin_elementwise_max(bt2, C23) - __builtin_elementwise_max(bn2, C23);
            a45 += __builtin_elementwise_max(bt2, C45) - __builtin_elementwise_max(bn2, C45);
            a67 += __builtin_elementwise_max(bt2, C67) - __builtin_elementwise_max(bn2, C67);
            a89 += __builtin_elementwise_max(bt2, C89) - __builtin_elementwise_max(bn2, C89);
        }
    }

    // expand 6-bit fields -> two u64 with 12-bit fields (wave-sum safe: <=52*64=3328<4096)
    unsigned long long lo = 0ull, hi = 0ull;
    #pragma unroll
    for (int k = 0; k < 5; ++k) {
        lo += ((hcnt >> (6 * k))       & 63ull) << (12 * k);
        hi += ((hcnt >> (6 * (k + 5))) & 63ull) << (12 * k);
    }
    float r10[10] = {a01.x, a01.y, a23.x, a23.y, a45.x, a45.y, a67.x, a67.y, a89.x, a89.y};
    #pragma unroll
    for (int off = 32; off > 0; off >>= 1) {
        #pragma unroll
        for (int k = 0; k < 10; ++k) r10[k] += __shfl_down(r10[k], off);
        lo += __shfl_down(lo, off);
        hi += __shfl_down(hi, off);
    }

    __shared__ float              sf[4][10];
    __shared__ unsigned long long sc[4][2];
    const int wave = threadIdx.x >> 6;
    const int lane = threadIdx.x & 63;
    if (lane == 0) {
        #pragma unroll
        for (int k = 0; k < 10; ++k) sf[wave][k] = r10[k];
        sc[wave][0] = lo; sc[wave][1] = hi;
    }
    __syncthreads();
    const int t = threadIdx.x;
    if (t < 10) {
        const float s = sf[0][t] + sf[1][t] + sf[2][t] + sf[3][t];
        atomicAdd(&wsll[t], (unsigned long long)(long long)((double)s * kScale));
    } else if (t < 20) {
        const int b = t - 10;
        const int half = (b < 5) ? 0 : 1;
        const int sh = 12 * (b < 5 ? b : b - 5);
        unsigned s = 0;
        #pragma unroll
        for (int w = 0; w < 4; ++w) s += (unsigned)((sc[w][half] >> sh) & 4095ull);
        atomicAdd(&wsu[b], s);
    }
}

__global__ void ghmc_final(const unsigned long long* __restrict__ wsll,
                           const unsigned* __restrict__ wsu,
                           float* __restrict__ out)
{
    if (threadIdx.x == 0 && blockIdx.x == 0) {
        const double cj[10] = {0.0,
            0.10536051565782630, 0.22314355131420976, 0.35667494393873245,
            0.51082562376599072, 0.69314718055994531, 0.91629073187415511,
            1.20397280432593600, 1.60943791243410040, 2.30258509299404570};
        double N[10], cnt[11], cum[11];
        for (int k = 0; k < 10; ++k) N[k] = (double)wsu[k];
        cnt[10] = 0.0;
        for (int j = 9; j >= 0; --j) cnt[j] = cnt[j + 1] + N[j];
        cum[10] = 0.0;
        cum[0] = (double)wsll[0] / kScale;                       // T (c=0 exact)
        for (int j = 1; j <= 9; ++j) {
            const double acc = (double)wsll[j] / kScale;
            cum[j] = acc - cj[j] * ((double)kNElem - cnt[j]);
        }
        double loss = 0.0, n = 0.0;
        for (int k = 0; k < 10; ++k) {
            if (N[k] > 0.0) { n += 1.0; loss += (cum[k] - cum[k + 1]) / N[k]; }
        }
        out[0] = (float)(loss / (n > 1.0 ? n : 1.0));
    }
}

extern "C" void kernel_launch(void* const* d_in, const int* in_sizes, int n_in,
                              void* d_out, int out_size, void* d_ws, size_t ws_size,
                              hipStream_t stream)
{
    const float* logits = (const float*)d_in[0];
    const int*   tgt    = (const int*)d_in[1];
    unsigned long long* wsll = (unsigned long long*)d_ws;        // 10 x u64
    unsigned*           wsu  = (unsigned*)((char*)d_ws + 80);    // 10 x u32
    hipMemsetAsync(d_ws, 0, 120, stream);
    ghmc_main<<<kBlocks, kThreads, 0, stream>>>(logits, tgt, wsll, wsu);
    ghmc_final<<<1, 64, 0, stream>>>(wsll, wsu, (float*)d_out);
}